// Round 1
// baseline (46.480 us; speedup 1.0000x reference)
//
#include <hip/hip_runtime.h>
#include <hip/hip_bf16.h>
#include <stdint.h>

#define LRELU_ALPHA 0.2f
#define NEG_INF -9000000000000000.0f
#define NB 32768
#define NTASKS (NB/16)

typedef float f32x4 __attribute__((ext_vector_type(4)));
typedef short s16x8 __attribute__((ext_vector_type(8)));

__device__ __forceinline__ unsigned short f2bf(float f){
  unsigned int u = __float_as_uint(f);
  u += 0x7fffu + ((u >> 16) & 1u);   // round-to-nearest-even
  return (unsigned short)(u >> 16);
}

// ws layout (ushort units): [0,16384) W^T bf16 swizzled; [16384,20480) W2eff^T bf16 swizzled
__global__ void prep_kernel(const float* __restrict__ W, const float* __restrict__ W2,
                            unsigned short* __restrict__ wsp){
  int t = blockIdx.x * blockDim.x + threadIdx.x;
  if (t < 64*256){
    int o = t & 63, k = t >> 6;
    wsp[o*256 + (k ^ ((o & 7) << 3))] = f2bf(W[k*64 + o]);
  }
  if (t < 64*64){
    int o = t & 63, c = t >> 6;
    float s = 0.f;
    #pragma unroll
    for (int h = 0; h < 8; ++h) s += W2[(h*64 + c)*64 + o];
    wsp[16384 + o*64 + (c ^ ((o & 7) << 3))] = f2bf(s);
  }
}

__launch_bounds__(256, 3)
__global__ void gat_kernel(const float* __restrict__ x, const float* __restrict__ adj,
                           const float* __restrict__ a, const float* __restrict__ a2,
                           const float* __restrict__ fc_w, const float* __restrict__ fc_b,
                           const unsigned short* __restrict__ wsp,
                           float* __restrict__ out){
  // LDS: [0,16384) W^T ; [16384,20480) W2eff^T ; [20480,24576) per-wave h1 scratch
  __shared__ __align__(16) unsigned short smem[24576];
  const int tid = threadIdx.x;
  {
    const uint4* src = (const uint4*)wsp;
    uint4* dst = (uint4*)smem;
    #pragma unroll
    for (int i = 0; i < 10; ++i) dst[tid + 256*i] = src[tid + 256*i];
  }
  __syncthreads();

  const int p  = tid & 15;        // low lane bits: A-row / B-col / C-col
  const int g  = (tid >> 4) & 3;  // 16-lane group within wave (owns graph g)
  const int wv = tid >> 6;        // wave id in block
  const int lbase = tid & 48;     // wave-relative group base lane

  float aS[4], aD[4], a2S[4], a2D[4], fw[4];
  #pragma unroll
  for (int ct = 0; ct < 4; ++ct){
    aS[ct]  = a[ct*16 + p];
    aD[ct]  = a[64 + ct*16 + p];
    a2S[ct] = a2[ct*16 + p];
    a2D[ct] = a2[64 + ct*16 + p];
    fw[ct]  = fc_w[ct*16 + p];
  }
  const float fcb = fc_b[0];
  const int hbase = 20480 + wv*1024;

  for (int it = blockIdx.x; it < NTASKS; it += gridDim.x){
    const int b0 = it*16 + wv*4;                 // wave's 4 graphs: b0..b0+3
    const float adjv = adj[(size_t)(b0 + g)*16 + p];  // adj[b0+g][p]

    // ---------------- GEMM1: Wh = x @ W (16 rows x 64 cols, K=256) ----------------
    f32x4 acc[4];
    #pragma unroll
    for (int ct = 0; ct < 4; ++ct) acc[ct] = (f32x4){0.f,0.f,0.f,0.f};
    const float* xrow = x + ((size_t)(b0 + (p >> 2))*4 + (p & 3))*256 + g*8;
    #pragma unroll
    for (int kk = 0; kk < 8; ++kk){
      float4 f0 = *(const float4*)(xrow + kk*32);
      float4 f1 = *(const float4*)(xrow + kk*32 + 4);
      union { s16x8 v; unsigned short u[8]; } af;
      af.u[0]=f2bf(f0.x); af.u[1]=f2bf(f0.y); af.u[2]=f2bf(f0.z); af.u[3]=f2bf(f0.w);
      af.u[4]=f2bf(f1.x); af.u[5]=f2bf(f1.y); af.u[6]=f2bf(f1.z); af.u[7]=f2bf(f1.w);
      const int kb = kk*32 + g*8;
      #pragma unroll
      for (int ct = 0; ct < 4; ++ct){
        const int o = ct*16 + p;
        s16x8 bf = *(const s16x8*)&smem[o*256 + (kb ^ ((o & 7) << 3))];
        acc[ct] = __builtin_amdgcn_mfma_f32_16x16x32_bf16(af.v, bf, acc[ct], 0, 0, 0);
      }
    }
    // acc[ct][r] = Wh[4g+r][ct*16+p]

    // ---------------- layer-1 attention (group g handles graph b0+g) ----------------
    float fs[4], fd[4];
    #pragma unroll
    for (int r = 0; r < 4; ++r){
      float s1 = 0.f, s2 = 0.f;
      #pragma unroll
      for (int ct = 0; ct < 4; ++ct){ s1 += acc[ct][r]*aS[ct]; s2 += acc[ct][r]*aD[ct]; }
      fs[r] = s1; fd[r] = s2;
    }
    #pragma unroll
    for (int msk = 1; msk < 16; msk <<= 1){
      #pragma unroll
      for (int r = 0; r < 4; ++r){
        fs[r] += __shfl_xor(fs[r], msk);
        fd[r] += __shfl_xor(fd[r], msk);
      }
    }
    // lane p computes e-entry (i=p>>2, j=p&3)
    float fsi = (p & 8) ? ((p & 4) ? fs[3] : fs[2]) : ((p & 4) ? fs[1] : fs[0]);
    float fdj = (p & 2) ? ((p & 1) ? fd[3] : fd[2]) : ((p & 1) ? fd[1] : fd[0]);
    float ev = fsi + fdj;
    ev = (ev > 0.f) ? ev : LRELU_ALPHA*ev;
    ev = (adjv > 0.f) ? ev : NEG_INF;
    float mx = fmaxf(ev, __shfl_xor(ev, 1));
    mx = fmaxf(mx, __shfl_xor(mx, 2));
    float pe = __expf(ev - mx);
    float se = pe + __shfl_xor(pe, 1);
    se += __shfl_xor(se, 2);
    const float att = pe / se;

    // hp = att @ Wh ; h1 = elu(hp) -> wave-private LDS (bf16, swizzled)
    #pragma unroll
    for (int r = 0; r < 4; ++r){
      float b0a = __shfl(att, lbase + r*4 + 0);
      float b1a = __shfl(att, lbase + r*4 + 1);
      float b2a = __shfl(att, lbase + r*4 + 2);
      float b3a = __shfl(att, lbase + r*4 + 3);
      const int mr = g*4 + r;
      #pragma unroll
      for (int ct = 0; ct < 4; ++ct){
        float hp = b0a*acc[ct][0] + b1a*acc[ct][1] + b2a*acc[ct][2] + b3a*acc[ct][3];
        hp = (hp > 0.f) ? hp : expm1f(hp);
        const int c = ct*16 + p;
        smem[hbase + mr*64 + (c ^ ((mr & 7) << 3))] = f2bf(hp);
      }
    }
    asm volatile("" ::: "memory");  // keep ds_reads below after ds_writes above

    // ---------------- GEMM2: Wh2 = h1 @ W2eff (16 x 64, K=64) ----------------
    f32x4 acc2[4];
    #pragma unroll
    for (int ct = 0; ct < 4; ++ct) acc2[ct] = (f32x4){0.f,0.f,0.f,0.f};
    #pragma unroll
    for (int kk = 0; kk < 2; ++kk){
      const int kb = kk*32 + g*8;
      s16x8 a2f = *(const s16x8*)&smem[hbase + p*64 + (kb ^ ((p & 7) << 3))];
      #pragma unroll
      for (int ct = 0; ct < 4; ++ct){
        const int o = ct*16 + p;
        s16x8 b2f = *(const s16x8*)&smem[16384 + o*64 + (kb ^ ((o & 7) << 3))];
        acc2[ct] = __builtin_amdgcn_mfma_f32_16x16x32_bf16(a2f, b2f, acc2[ct], 0, 0, 0);
      }
    }

    // ---------------- layer-2 attention (row 0 only) + fc ----------------
    float fd2[4], sv[4], fs20 = 0.f;
    #pragma unroll
    for (int r = 0; r < 4; ++r){
      float s1 = 0.f, s2 = 0.f;
      #pragma unroll
      for (int ct = 0; ct < 4; ++ct){ s1 += acc2[ct][r]*a2D[ct]; s2 += acc2[ct][r]*fw[ct]; }
      fd2[r] = s1; sv[r] = s2;
    }
    #pragma unroll
    for (int ct = 0; ct < 4; ++ct) fs20 += acc2[ct][0]*a2S[ct];
    #pragma unroll
    for (int msk = 1; msk < 16; msk <<= 1){
      #pragma unroll
      for (int r = 0; r < 4; ++r){
        fd2[r] += __shfl_xor(fd2[r], msk);
        sv[r]  += __shfl_xor(sv[r],  msk);
      }
      fs20 += __shfl_xor(fs20, msk);
    }
    float e2[4];
    #pragma unroll
    for (int j = 0; j < 4; ++j){
      float adj0 = __shfl(adjv, lbase + j);         // adj[b][0][j]
      float tv = fs20 + fd2[j];
      tv = (tv > 0.f) ? tv : LRELU_ALPHA*tv;
      e2[j] = (adj0 > 0.f) ? tv : NEG_INF;
    }
    float m2 = fmaxf(fmaxf(e2[0], e2[1]), fmaxf(e2[2], e2[3]));
    float s2s = 0.f, ov = 0.f;
    #pragma unroll
    for (int j = 0; j < 4; ++j){
      float pj = __expf(e2[j] - m2);
      s2s += pj; ov += pj*sv[j];
    }
    if (p == 0) out[b0 + g] = ov/s2s + fcb;
  }
}

extern "C" void kernel_launch(void* const* d_in, const int* in_sizes, int n_in,
                              void* d_out, int out_size, void* d_ws, size_t ws_size,
                              hipStream_t stream){
  (void)in_sizes; (void)n_in; (void)out_size; (void)ws_size;
  const float* x   = (const float*)d_in[0];
  const float* adj = (const float*)d_in[1];
  const float* W   = (const float*)d_in[2];
  const float* a   = (const float*)d_in[3];
  const float* W2  = (const float*)d_in[4];
  const float* a2  = (const float*)d_in[5];
  const float* fcw = (const float*)d_in[6];
  const float* fcb = (const float*)d_in[7];
  float* out = (float*)d_out;
  unsigned short* wsp = (unsigned short*)d_ws;

  hipLaunchKernelGGL(prep_kernel, dim3(64), dim3(256), 0, stream, W, W2, wsp);
  hipLaunchKernelGGL(gat_kernel, dim3(1024), dim3(256), 0, stream,
                     x, adj, a, a2, fcw, fcb, wsp, out);
}

// Round 2
// 38.490 us; speedup vs baseline: 1.2076x; 1.2076x over previous
//
#include <hip/hip_runtime.h>
#include <hip/hip_bf16.h>
#include <stdint.h>

#define LRELU_ALPHA 0.2f
#define NEG_INF -9000000000000000.0f
#define NB 32768
#define NTASKS (NB/16)
#define GRID 768

typedef float f32x4 __attribute__((ext_vector_type(4)));
typedef short s16x8 __attribute__((ext_vector_type(8)));

__device__ __forceinline__ unsigned short f2bf(float f){
  unsigned int u = __float_as_uint(f);
  u += 0x7fffu + ((u >> 16) & 1u);   // round-to-nearest-even
  return (unsigned short)(u >> 16);
}

// ws layout (ushort units): [0,16384) W^T bf16 swizzled; [16384,20480) W2eff^T bf16 swizzled
__global__ void prep_kernel(const float* __restrict__ W, const float* __restrict__ W2,
                            unsigned short* __restrict__ wsp){
  int t = blockIdx.x * blockDim.x + threadIdx.x;
  if (t < 64*256){
    int o = t & 63, k = t >> 6;
    wsp[o*256 + (k ^ ((o & 7) << 3))] = f2bf(W[k*64 + o]);
  }
  if (t < 64*64){
    int o = t & 63, c = t >> 6;
    float s = 0.f;
    #pragma unroll
    for (int h = 0; h < 8; ++h) s += W2[(h*64 + c)*64 + o];
    wsp[16384 + o*64 + (c ^ ((o & 7) << 3))] = f2bf(s);
  }
}

__launch_bounds__(256, 3)
__global__ void gat_kernel(const float* __restrict__ x, const float* __restrict__ adj,
                           const float* __restrict__ a, const float* __restrict__ a2,
                           const float* __restrict__ fc_w, const float* __restrict__ fc_b,
                           const unsigned short* __restrict__ wsp,
                           float* __restrict__ out){
  // LDS: [0,16384) W^T ; [16384,20480) W2eff^T ; [20480,24576) per-wave h1 scratch
  __shared__ __align__(16) unsigned short smem[24576];
  const int tid = threadIdx.x;
  {
    const uint4* src = (const uint4*)wsp;
    uint4* dst = (uint4*)smem;
    #pragma unroll
    for (int i = 0; i < 10; ++i) dst[tid + 256*i] = src[tid + 256*i];
  }
  __syncthreads();

  const int p  = tid & 15;        // low lane bits: A-row / B-col / C-col
  const int g  = (tid >> 4) & 3;  // 16-lane group within wave (owns graph g)
  const int wv = tid >> 6;        // wave id in block
  const int lbase = tid & 48;     // wave-relative group base lane

  float aS[4], aD[4], a2S[4], a2D[4], fw[4];
  #pragma unroll
  for (int ct = 0; ct < 4; ++ct){
    aS[ct]  = a[ct*16 + p];
    aD[ct]  = a[64 + ct*16 + p];
    a2S[ct] = a2[ct*16 + p];
    a2D[ct] = a2[64 + ct*16 + p];
    fw[ct]  = fc_w[ct*16 + p];
  }
  const float fcb = fc_b[0];
  const int hbase = 20480 + wv*1024;

  // ---- software-pipelined x/adj prefetch registers ----
  float4 xb[8][2];
  float adv;
  {
    const int b0 = blockIdx.x*16 + wv*4;
    const float* xrow = x + ((size_t)(b0 + (p >> 2))*4 + (p & 3))*256 + g*8;
    #pragma unroll
    for (int kk = 0; kk < 8; ++kk){
      xb[kk][0] = *(const float4*)(xrow + kk*32);
      xb[kk][1] = *(const float4*)(xrow + kk*32 + 4);
    }
    adv = adj[(size_t)(b0 + g)*16 + p];
  }

  for (int it = blockIdx.x; it < NTASKS; it += GRID){
    const int b0 = it*16 + wv*4;                 // wave's 4 graphs: b0..b0+3
    const float adjv = adv;                      // adj[b0+g][p] (prefetched)

    // ---------------- GEMM1: Wh = x @ W (16 rows x 64 cols, K=256) ----------------
    f32x4 acc[4];
    #pragma unroll
    for (int ct = 0; ct < 4; ++ct) acc[ct] = (f32x4){0.f,0.f,0.f,0.f};
    #pragma unroll
    for (int kk = 0; kk < 8; ++kk){
      float4 f0 = xb[kk][0];
      float4 f1 = xb[kk][1];
      union { s16x8 v; __hip_bfloat162 h2[4]; } af;
      af.h2[0] = __float22bfloat162_rn(make_float2(f0.x, f0.y));
      af.h2[1] = __float22bfloat162_rn(make_float2(f0.z, f0.w));
      af.h2[2] = __float22bfloat162_rn(make_float2(f1.x, f1.y));
      af.h2[3] = __float22bfloat162_rn(make_float2(f1.z, f1.w));
      const int kb = kk*32 + g*8;
      #pragma unroll
      for (int ct = 0; ct < 4; ++ct){
        const int o = ct*16 + p;
        s16x8 bf = *(const s16x8*)&smem[o*256 + (kb ^ ((o & 7) << 3))];
        acc[ct] = __builtin_amdgcn_mfma_f32_16x16x32_bf16(af.v, bf, acc[ct], 0, 0, 0);
      }
    }
    // acc[ct][r] = Wh[4g+r][ct*16+p]

    // ---- issue next iteration's loads NOW; they fly during attention/GEMM2 ----
    {
      const int itn = it + GRID;
      if (itn < NTASKS){
        const int b0n = itn*16 + wv*4;
        const float* xrow = x + ((size_t)(b0n + (p >> 2))*4 + (p & 3))*256 + g*8;
        #pragma unroll
        for (int kk = 0; kk < 8; ++kk){
          xb[kk][0] = *(const float4*)(xrow + kk*32);
          xb[kk][1] = *(const float4*)(xrow + kk*32 + 4);
        }
        adv = adj[(size_t)(b0n + g)*16 + p];
      }
    }

    // ---------------- layer-1 attention (group g handles graph b0+g) ----------------
    float fs[4], fd[4];
    #pragma unroll
    for (int r = 0; r < 4; ++r){
      float s1 = 0.f, s2 = 0.f;
      #pragma unroll
      for (int ct = 0; ct < 4; ++ct){ s1 += acc[ct][r]*aS[ct]; s2 += acc[ct][r]*aD[ct]; }
      fs[r] = s1; fd[r] = s2;
    }
    #pragma unroll
    for (int msk = 1; msk < 16; msk <<= 1){
      #pragma unroll
      for (int r = 0; r < 4; ++r){
        fs[r] += __shfl_xor(fs[r], msk);
        fd[r] += __shfl_xor(fd[r], msk);
      }
    }
    // lane p computes e-entry (i=p>>2, j=p&3)
    float fsi = (p & 8) ? ((p & 4) ? fs[3] : fs[2]) : ((p & 4) ? fs[1] : fs[0]);
    float fdj = (p & 2) ? ((p & 1) ? fd[3] : fd[2]) : ((p & 1) ? fd[1] : fd[0]);
    float ev = fsi + fdj;
    ev = (ev > 0.f) ? ev : LRELU_ALPHA*ev;
    ev = (adjv > 0.f) ? ev : NEG_INF;
    float mx = fmaxf(ev, __shfl_xor(ev, 1));
    mx = fmaxf(mx, __shfl_xor(mx, 2));
    float pe = __expf(ev - mx);
    float se = pe + __shfl_xor(pe, 1);
    se += __shfl_xor(se, 2);
    const float att = pe / se;

    // hp = att @ Wh ; h1 = elu(hp) -> wave-private LDS (bf16, swizzled)
    #pragma unroll
    for (int r = 0; r < 4; ++r){
      float b0a = __shfl(att, lbase + r*4 + 0);
      float b1a = __shfl(att, lbase + r*4 + 1);
      float b2a = __shfl(att, lbase + r*4 + 2);
      float b3a = __shfl(att, lbase + r*4 + 3);
      const int mr = g*4 + r;
      #pragma unroll
      for (int ct = 0; ct < 4; ++ct){
        float hp = b0a*acc[ct][0] + b1a*acc[ct][1] + b2a*acc[ct][2] + b3a*acc[ct][3];
        hp = (hp > 0.f) ? hp : (__expf(hp) - 1.0f);   // elu via hw exp (bf16-accurate)
        const int c = ct*16 + p;
        smem[hbase + mr*64 + (c ^ ((mr & 7) << 3))] = f2bf(hp);
      }
    }
    asm volatile("" ::: "memory");  // keep ds_reads below after ds_writes above

    // ---------------- GEMM2: Wh2 = h1 @ W2eff (16 x 64, K=64) ----------------
    f32x4 acc2[4];
    #pragma unroll
    for (int ct = 0; ct < 4; ++ct) acc2[ct] = (f32x4){0.f,0.f,0.f,0.f};
    #pragma unroll
    for (int kk = 0; kk < 2; ++kk){
      const int kb = kk*32 + g*8;
      s16x8 a2f = *(const s16x8*)&smem[hbase + p*64 + (kb ^ ((p & 7) << 3))];
      #pragma unroll
      for (int ct = 0; ct < 4; ++ct){
        const int o = ct*16 + p;
        s16x8 b2f = *(const s16x8*)&smem[16384 + o*64 + (kb ^ ((o & 7) << 3))];
        acc2[ct] = __builtin_amdgcn_mfma_f32_16x16x32_bf16(a2f, b2f, acc2[ct], 0, 0, 0);
      }
    }

    // ---------------- layer-2 attention (row 0 only) + fc ----------------
    float fd2[4], sv[4], fs20 = 0.f;
    #pragma unroll
    for (int r = 0; r < 4; ++r){
      float s1 = 0.f, s2 = 0.f;
      #pragma unroll
      for (int ct = 0; ct < 4; ++ct){ s1 += acc2[ct][r]*a2D[ct]; s2 += acc2[ct][r]*fw[ct]; }
      fd2[r] = s1; sv[r] = s2;
    }
    #pragma unroll
    for (int ct = 0; ct < 4; ++ct) fs20 += acc2[ct][0]*a2S[ct];
    #pragma unroll
    for (int msk = 1; msk < 16; msk <<= 1){
      #pragma unroll
      for (int r = 0; r < 4; ++r){
        fd2[r] += __shfl_xor(fd2[r], msk);
        sv[r]  += __shfl_xor(sv[r],  msk);
      }
      fs20 += __shfl_xor(fs20, msk);
    }
    float e2[4];
    #pragma unroll
    for (int j = 0; j < 4; ++j){
      float adj0 = __shfl(adjv, lbase + j);         // adj[b][0][j]
      float tv = fs20 + fd2[j];
      tv = (tv > 0.f) ? tv : LRELU_ALPHA*tv;
      e2[j] = (adj0 > 0.f) ? tv : NEG_INF;
    }
    float m2 = fmaxf(fmaxf(e2[0], e2[1]), fmaxf(e2[2], e2[3]));
    float s2s = 0.f, ov = 0.f;
    #pragma unroll
    for (int j = 0; j < 4; ++j){
      float pj = __expf(e2[j] - m2);
      s2s += pj; ov += pj*sv[j];
    }
    if (p == 0) out[b0 + g] = ov/s2s + fcb;
  }
}

extern "C" void kernel_launch(void* const* d_in, const int* in_sizes, int n_in,
                              void* d_out, int out_size, void* d_ws, size_t ws_size,
                              hipStream_t stream){
  (void)in_sizes; (void)n_in; (void)out_size; (void)ws_size;
  const float* x   = (const float*)d_in[0];
  const float* adj = (const float*)d_in[1];
  const float* W   = (const float*)d_in[2];
  const float* a   = (const float*)d_in[3];
  const float* W2  = (const float*)d_in[4];
  const float* a2  = (const float*)d_in[5];
  const float* fcw = (const float*)d_in[6];
  const float* fcb = (const float*)d_in[7];
  float* out = (float*)d_out;
  unsigned short* wsp = (unsigned short*)d_ws;

  hipLaunchKernelGGL(prep_kernel, dim3(64), dim3(256), 0, stream, W, W2, wsp);
  hipLaunchKernelGGL(gat_kernel, dim3(GRID), dim3(256), 0, stream,
                     x, adj, a, a2, fcw, fcb, wsp, out);
}